// Round 6
// baseline (54.678 us; speedup 1.0000x reference)
//
#include <hip/hip_runtime.h>
#include <stdint.h>

#define NUM_PIDS 20000
#define HBLK_MAX 128           // histogram partial tables (one per hist block)
#define NCH      8             // reduce stage-1 fan-in chunks
#define FIXB     512.0f        // 2^9 fixed point for per-hit mse (17-bit field)
#define FXMASK   0x1FFFFu
// packed u32 per hit: pid in bits[17:31], fx in bits[0:16]; 0 = excluded hit
// LDS / tbl cell: count in bits[24:31], fx-sum in bits[0:23]
// tmp u64: count in bits[40:63], fx-sum in bits[0:39]

// ws: [ u32 packed[n] | u32 tbl[hblk][NUM_PIDS] | u64 tmp[NCH][NUM_PIDS] | float acc[2] ]

__global__ void zero_acc_kernel(float* __restrict__ acc) {
    if (threadIdx.x < 2) acc[threadIdx.x] = 0.0f;
}

__device__ __forceinline__ float mse_pair(float4 a0, float4 a1, float4 b0, float4 b1) {
    float d0 = a0.x - b0.x, d1 = a0.y - b0.y;
    float d2 = a0.z - b0.z, d3 = a0.w - b0.w;
    float d4 = a1.x - b1.x, d5 = a1.y - b1.y;
    float d6 = a1.z - b1.z, d7 = a1.w - b1.w;
    return d0*d0 + d1*d1 + d2*d2 + d3*d3 + d4*d4 + d5*d5 + d6*d6 + d7*d7;
}

__device__ __forceinline__ unsigned int pack_hit(int p, int r, float mse) {
    unsigned int fx = (unsigned int)fminf(mse * FIXB + 0.5f, 131071.0f);
    return (p > 0 && r > 0) ? (((unsigned int)p << 17) | fx) : 0u;
}

// One quad (4 hits) per thread, straight-line 18-load cluster:
// int4 pid + int4 recon + 16 contiguous float4 (128B pred + 128B track).
// launch_bounds(256,2) gives the allocator headroom so all 18 loads stay
// in flight (R5's VGPR=8 codegen serialized into load->wait->use chains).
__global__ void __launch_bounds__(256, 2) mse_kernel(
        const float4* __restrict__ pred4,
        const float4* __restrict__ track4,
        const int4* __restrict__ pid4,
        const int4* __restrict__ recon4,
        const int* __restrict__ pid,
        const int* __restrict__ recon,
        uint4* __restrict__ packed4,
        unsigned int* __restrict__ packed,
        int Q /* n/4 */, int n) {
    int t = blockIdx.x * 256 + threadIdx.x;
    int T = gridDim.x * 256;
    for (int q = t; q < Q; q += T) {
        size_t f = (size_t)q * 8;
        int4 P = pid4[q];
        int4 R = recon4[q];
        float4 a0 = pred4[f+0], a1 = pred4[f+1], a2 = pred4[f+2], a3 = pred4[f+3];
        float4 a4 = pred4[f+4], a5 = pred4[f+5], a6 = pred4[f+6], a7 = pred4[f+7];
        float4 b0 = track4[f+0], b1 = track4[f+1], b2 = track4[f+2], b3 = track4[f+3];
        float4 b4 = track4[f+4], b5 = track4[f+5], b6 = track4[f+6], b7 = track4[f+7];
        float m0 = mse_pair(a0, a1, b0, b1);
        float m1 = mse_pair(a2, a3, b2, b3);
        float m2 = mse_pair(a4, a5, b4, b5);
        float m3 = mse_pair(a6, a7, b6, b7);
        uint4 o;
        o.x = pack_hit(P.x, R.x, m0);
        o.y = pack_hit(P.y, R.y, m1);
        o.z = pack_hit(P.z, R.z, m2);
        o.w = pack_hit(P.w, R.w, m3);
        packed4[q] = o;
    }
    // tail hits [4Q, n) handled scalarly (n%4==0 in practice -> no-op)
    int tail = n - 4 * Q;
    if (t < tail) {
        int h = 4 * Q + t;
        float4 a0 = pred4[2*(size_t)h], a1 = pred4[2*(size_t)h+1];
        float4 b0 = track4[2*(size_t)h], b1 = track4[2*(size_t)h+1];
        packed[h] = pack_hit(pid[h], recon[h], mse_pair(a0, a1, b0, b1));
    }
}

__global__ void __launch_bounds__(1024) hist_kernel(
        const uint4* __restrict__ packed4,
        unsigned int* __restrict__ tbl,
        int n4,
        const unsigned int* __restrict__ packed,
        int n) {
    __shared__ unsigned int bins[NUM_PIDS];        // 80 KB -> 2 blocks/CU
    for (int j = threadIdx.x; j < NUM_PIDS; j += 1024) bins[j] = 0u;
    __syncthreads();
    int t = blockIdx.x * 1024 + threadIdx.x;
    int stride = gridDim.x * 1024;
    for (; t < n4; t += stride) {
        uint4 v = packed4[t];
        unsigned int p;
        p = v.x >> 17; if (p) atomicAdd(&bins[p], (1u << 24) | (v.x & FXMASK));
        p = v.y >> 17; if (p) atomicAdd(&bins[p], (1u << 24) | (v.y & FXMASK));
        p = v.z >> 17; if (p) atomicAdd(&bins[p], (1u << 24) | (v.z & FXMASK));
        p = v.w >> 17; if (p) atomicAdd(&bins[p], (1u << 24) | (v.w & FXMASK));
    }
    for (int i = 4 * n4 + blockIdx.x * 1024 + threadIdx.x; i < n; i += stride) {
        unsigned int c = packed[i];
        unsigned int p = c >> 17;
        if (p) atomicAdd(&bins[p], (1u << 24) | (c & FXMASK));
    }
    __syncthreads();
    unsigned int* my = tbl + (size_t)blockIdx.x * NUM_PIDS;
    for (int j = threadIdx.x; j < NUM_PIDS; j += 1024) my[j] = bins[j];
}

// stage 1: sum a chunk of block-tables into u64 tmp[chunk][pid]
__global__ void __launch_bounds__(256) reduce1_kernel(
        const unsigned int* __restrict__ tbl,
        unsigned long long* __restrict__ tmp,
        int nblk) {
    int p = blockIdx.x * 256 + threadIdx.x;
    int c = blockIdx.y;
    if (p >= NUM_PIDS) return;
    int cs = (nblk + NCH - 1) / NCH;
    int b0 = c * cs, b1 = min(nblk, b0 + cs);
    unsigned long long sfx = 0ULL, cnt = 0ULL;
    for (int b = b0; b < b1; ++b) {
        unsigned int v = tbl[(size_t)b * NUM_PIDS + p];   // coalesced
        sfx += (unsigned long long)(v & 0xFFFFFFu);
        cnt += (unsigned long long)(v >> 24);
    }
    tmp[(size_t)c * NUM_PIDS + p] = (cnt << 40) | sfx;
}

// stage 2: fold NCH chunks, per-pid mean, block-reduce, 2 atomics/block
__global__ void __launch_bounds__(256) reduce2_kernel(
        const unsigned long long* __restrict__ tmp,
        float* __restrict__ acc) {
    int p = blockIdx.x * 256 + threadIdx.x;
    float mean = 0.0f, pres = 0.0f;
    if (p >= 1 && p < NUM_PIDS) {
        unsigned long long s = 0ULL;
        #pragma unroll
        for (int c = 0; c < NCH; ++c) s += tmp[(size_t)c * NUM_PIDS + p];
        unsigned long long cnt = s >> 40;
        if (cnt > 0) {
            double sum = (double)(s & ((1ULL << 40) - 1)) * (1.0 / 512.0);
            mean = (float)(sum / (double)cnt);
            pres = 1.0f;
        }
    }
    #pragma unroll
    for (int off = 32; off > 0; off >>= 1) {
        mean += __shfl_down(mean, off);
        pres += __shfl_down(pres, off);
    }
    __shared__ float smean[4], spres[4];
    int wave = threadIdx.x >> 6, lane = threadIdx.x & 63;
    if (lane == 0) { smean[wave] = mean; spres[wave] = pres; }
    __syncthreads();
    if (threadIdx.x == 0) {
        atomicAdd(&acc[0], smean[0] + smean[1] + smean[2] + smean[3]);
        atomicAdd(&acc[1], spres[0] + spres[1] + spres[2] + spres[3]);
    }
}

__global__ void final_kernel(const float* __restrict__ acc,
                             float* __restrict__ out) {
    if (threadIdx.x == 0 && blockIdx.x == 0) {
        float K = acc[1];
        out[0] = (K > 0.0f) ? (100.0f * acc[0] / K) : 0.0f;
    }
}

extern "C" void kernel_launch(void* const* d_in, const int* in_sizes, int n_in,
                              void* d_out, int out_size, void* d_ws, size_t ws_size,
                              hipStream_t stream) {
    // setup_inputs order: W(0) beta(1) H(2) pred(3) Y(4) particle_id(5)
    //                     track_params(6) reconstructable(7)
    const float* pred  = (const float*)d_in[3];
    const int*   pid   = (const int*)d_in[5];
    const float* track = (const float*)d_in[6];
    const int*   recon = (const int*)d_in[7];
    int n = in_sizes[5];   // N hits
    int Q = n / 4;

    size_t packed_bytes = (((size_t)n * 4) + 63) & ~(size_t)63;
    size_t tmp_bytes = (size_t)NCH * NUM_PIDS * 8;
    // adaptive histogram-table count
    int hblk = 8;
    if (ws_size > packed_bytes + tmp_bytes + 64 + (size_t)NUM_PIDS * 4) {
        size_t cap = (ws_size - packed_bytes - tmp_bytes - 64) / ((size_t)NUM_PIDS * 4);
        hblk = (int)(cap < HBLK_MAX ? cap : HBLK_MAX);
        if (hblk < 1) hblk = 1;
    }

    unsigned int* packed = (unsigned int*)d_ws;
    unsigned int* tbl = (unsigned int*)((char*)d_ws + packed_bytes);
    unsigned long long* tmp =
        (unsigned long long*)((char*)tbl + (size_t)hblk * NUM_PIDS * 4);
    float* acc = (float*)((char*)tmp + tmp_bytes);

    zero_acc_kernel<<<1, 64, 0, stream>>>(acc);
    // 2048*256 threads >= Q for n=2M -> effectively one straight-line
    // 18-load iteration per thread.
    mse_kernel<<<2048, 256, 0, stream>>>(
        (const float4*)pred, (const float4*)track,
        (const int4*)pid, (const int4*)recon,
        pid, recon,
        (uint4*)packed, packed, Q, n);
    hist_kernel<<<hblk, 1024, 0, stream>>>((const uint4*)packed, tbl, n / 4,
                                           packed, n);
    dim3 g1((NUM_PIDS + 255) / 256, NCH);
    reduce1_kernel<<<g1, 256, 0, stream>>>(tbl, tmp, hblk);
    reduce2_kernel<<<(NUM_PIDS + 255) / 256, 256, 0, stream>>>(tmp, acc);
    final_kernel<<<1, 64, 0, stream>>>(acc, (float*)d_out);
}

// Round 7
// 50.076 us; speedup vs baseline: 1.0919x; 1.0919x over previous
//
#include <hip/hip_runtime.h>
#include <stdint.h>

#define NUM_PIDS 20000
#define HBLK_MAX 128           // histogram partial tables (one per hist block)
#define NCH      8             // reduce stage-1 fan-in chunks
#define FIXB     512.0f        // 2^9 fixed point for per-hit mse (17-bit field)
#define FXMASK   0x1FFFFu
// packed u32 per hit: pid in bits[17:31], fx in bits[0:16]; 0 = excluded hit
// LDS / tbl cell: count in bits[24:31], fx-sum in bits[0:23]
// tmp u64: count in bits[40:63], fx-sum in bits[0:39]

// ws: [ u32 packed[n] | u32 tbl[hblk][NUM_PIDS] | u64 tmp[NCH][NUM_PIDS] | float acc[2] ]

typedef __attribute__((ext_vector_type(4))) float f32x4;
typedef __attribute__((ext_vector_type(2))) unsigned int u32x2;

__global__ void zero_acc_kernel(float* __restrict__ acc) {
    if (threadIdx.x < 2) acc[threadIdx.x] = 0.0f;
}

__device__ __forceinline__ unsigned int pack_hit(unsigned int p, unsigned int r, float mse) {
    unsigned int fx = (unsigned int)fminf(mse * FIXB + 0.5f, 131071.0f);
    return ((int)p > 0 && (int)r > 0) ? ((p << 17) | fx) : 0u;
}

// 2 hits per thread. The ENTIRE 10-load cluster is one inline-asm block with
// the vmcnt(0) inside: the compiler cannot serialize it, so every wave holds
// 144 B/lane of loads in flight (vs ~2 loads with compiler codegen, R4-R6).
__global__ void __launch_bounds__(256) mse_kernel(
        const char* __restrict__ pred,
        const char* __restrict__ track,
        const char* __restrict__ pid,
        const char* __restrict__ recon,
        u32x2* __restrict__ packed2,
        unsigned int* __restrict__ packed,
        int Q2 /* n/2 */, int n) {
    int t = blockIdx.x * 256 + threadIdx.x;
    int T = gridDim.x * 256;
    for (int q = t; q < Q2; q += T) {
        size_t off = (size_t)q * 64;           // 2 hits = 64 B of pred/track
        const char* pa = pred + off;
        const char* pb = track + off;
        const char* pp = pid + (size_t)q * 8;
        const char* pr = recon + (size_t)q * 8;
        f32x4 a0, a1, a2, a3, b0, b1, b2, b3;
        u32x2 P, R;
        asm volatile(
            "global_load_dwordx4 %0, %10, off\n\t"
            "global_load_dwordx4 %1, %10, off offset:16\n\t"
            "global_load_dwordx4 %2, %10, off offset:32\n\t"
            "global_load_dwordx4 %3, %10, off offset:48\n\t"
            "global_load_dwordx4 %4, %11, off\n\t"
            "global_load_dwordx4 %5, %11, off offset:16\n\t"
            "global_load_dwordx4 %6, %11, off offset:32\n\t"
            "global_load_dwordx4 %7, %11, off offset:48\n\t"
            "global_load_dwordx2 %8, %12, off\n\t"
            "global_load_dwordx2 %9, %13, off\n\t"
            "s_waitcnt vmcnt(0)"
            : "=&v"(a0), "=&v"(a1), "=&v"(a2), "=&v"(a3),
              "=&v"(b0), "=&v"(b1), "=&v"(b2), "=&v"(b3),
              "=&v"(P), "=&v"(R)
            : "v"(pa), "v"(pb), "v"(pp), "v"(pr)
            : "memory");
        __builtin_amdgcn_sched_barrier(0);
        float d0 = a0.x-b0.x, d1 = a0.y-b0.y, d2 = a0.z-b0.z, d3 = a0.w-b0.w;
        float d4 = a1.x-b1.x, d5 = a1.y-b1.y, d6 = a1.z-b1.z, d7 = a1.w-b1.w;
        float m0 = d0*d0+d1*d1+d2*d2+d3*d3 + d4*d4+d5*d5+d6*d6+d7*d7;
        float e0 = a2.x-b2.x, e1 = a2.y-b2.y, e2 = a2.z-b2.z, e3 = a2.w-b2.w;
        float e4 = a3.x-b3.x, e5 = a3.y-b3.y, e6 = a3.z-b3.z, e7 = a3.w-b3.w;
        float m1 = e0*e0+e1*e1+e2*e2+e3*e3 + e4*e4+e5*e5+e6*e6+e7*e7;
        u32x2 o;
        o.x = pack_hit(P.x, R.x, m0);
        o.y = pack_hit(P.y, R.y, m1);
        packed2[q] = o;
    }
    // tail hit if n is odd (n=2M even in practice)
    int tail = n - 2 * Q2;
    if (tail && t == 0) {
        int h = 2 * Q2;
        const float* pa = (const float*)(pred + (size_t)h * 32);
        const float* pb = (const float*)(track + (size_t)h * 32);
        float m = 0.0f;
        for (int k = 0; k < 8; ++k) { float d = pa[k] - pb[k]; m += d * d; }
        packed[h] = pack_hit(((const unsigned int*)pid)[h],
                             ((const unsigned int*)recon)[h], m);
    }
}

__global__ void __launch_bounds__(1024) hist_kernel(
        const uint4* __restrict__ packed4,
        unsigned int* __restrict__ tbl,
        int n4,
        const unsigned int* __restrict__ packed,
        int n) {
    __shared__ unsigned int bins[NUM_PIDS];        // 80 KB -> 2 blocks/CU
    for (int j = threadIdx.x; j < NUM_PIDS; j += 1024) bins[j] = 0u;
    __syncthreads();
    int t = blockIdx.x * 1024 + threadIdx.x;
    int stride = gridDim.x * 1024;
    for (; t < n4; t += stride) {
        uint4 v = packed4[t];
        unsigned int p;
        p = v.x >> 17; if (p) atomicAdd(&bins[p], (1u << 24) | (v.x & FXMASK));
        p = v.y >> 17; if (p) atomicAdd(&bins[p], (1u << 24) | (v.y & FXMASK));
        p = v.z >> 17; if (p) atomicAdd(&bins[p], (1u << 24) | (v.z & FXMASK));
        p = v.w >> 17; if (p) atomicAdd(&bins[p], (1u << 24) | (v.w & FXMASK));
    }
    for (int i = 4 * n4 + blockIdx.x * 1024 + threadIdx.x; i < n; i += stride) {
        unsigned int c = packed[i];
        unsigned int p = c >> 17;
        if (p) atomicAdd(&bins[p], (1u << 24) | (c & FXMASK));
    }
    __syncthreads();
    unsigned int* my = tbl + (size_t)blockIdx.x * NUM_PIDS;
    for (int j = threadIdx.x; j < NUM_PIDS; j += 1024) my[j] = bins[j];
}

// stage 1: sum a chunk of block-tables into u64 tmp[chunk][pid]
__global__ void __launch_bounds__(256) reduce1_kernel(
        const unsigned int* __restrict__ tbl,
        unsigned long long* __restrict__ tmp,
        int nblk) {
    int p = blockIdx.x * 256 + threadIdx.x;
    int c = blockIdx.y;
    if (p >= NUM_PIDS) return;
    int cs = (nblk + NCH - 1) / NCH;
    int b0 = c * cs, b1 = min(nblk, b0 + cs);
    unsigned long long sfx = 0ULL, cnt = 0ULL;
    for (int b = b0; b < b1; ++b) {
        unsigned int v = tbl[(size_t)b * NUM_PIDS + p];   // coalesced
        sfx += (unsigned long long)(v & 0xFFFFFFu);
        cnt += (unsigned long long)(v >> 24);
    }
    tmp[(size_t)c * NUM_PIDS + p] = (cnt << 40) | sfx;
}

// stage 2: fold NCH chunks, per-pid mean, block-reduce, 2 atomics/block
__global__ void __launch_bounds__(256) reduce2_kernel(
        const unsigned long long* __restrict__ tmp,
        float* __restrict__ acc) {
    int p = blockIdx.x * 256 + threadIdx.x;
    float mean = 0.0f, pres = 0.0f;
    if (p >= 1 && p < NUM_PIDS) {
        unsigned long long s = 0ULL;
        #pragma unroll
        for (int c = 0; c < NCH; ++c) s += tmp[(size_t)c * NUM_PIDS + p];
        unsigned long long cnt = s >> 40;
        if (cnt > 0) {
            double sum = (double)(s & ((1ULL << 40) - 1)) * (1.0 / 512.0);
            mean = (float)(sum / (double)cnt);
            pres = 1.0f;
        }
    }
    #pragma unroll
    for (int off = 32; off > 0; off >>= 1) {
        mean += __shfl_down(mean, off);
        pres += __shfl_down(pres, off);
    }
    __shared__ float smean[4], spres[4];
    int wave = threadIdx.x >> 6, lane = threadIdx.x & 63;
    if (lane == 0) { smean[wave] = mean; spres[wave] = pres; }
    __syncthreads();
    if (threadIdx.x == 0) {
        atomicAdd(&acc[0], smean[0] + smean[1] + smean[2] + smean[3]);
        atomicAdd(&acc[1], spres[0] + spres[1] + spres[2] + spres[3]);
    }
}

__global__ void final_kernel(const float* __restrict__ acc,
                             float* __restrict__ out) {
    if (threadIdx.x == 0 && blockIdx.x == 0) {
        float K = acc[1];
        out[0] = (K > 0.0f) ? (100.0f * acc[0] / K) : 0.0f;
    }
}

extern "C" void kernel_launch(void* const* d_in, const int* in_sizes, int n_in,
                              void* d_out, int out_size, void* d_ws, size_t ws_size,
                              hipStream_t stream) {
    // setup_inputs order: W(0) beta(1) H(2) pred(3) Y(4) particle_id(5)
    //                     track_params(6) reconstructable(7)
    const char* pred  = (const char*)d_in[3];
    const char* pid   = (const char*)d_in[5];
    const char* track = (const char*)d_in[6];
    const char* recon = (const char*)d_in[7];
    int n = in_sizes[5];   // N hits
    int Q2 = n / 2;

    size_t packed_bytes = (((size_t)n * 4) + 63) & ~(size_t)63;
    size_t tmp_bytes = (size_t)NCH * NUM_PIDS * 8;
    // adaptive histogram-table count
    int hblk = 8;
    if (ws_size > packed_bytes + tmp_bytes + 64 + (size_t)NUM_PIDS * 4) {
        size_t cap = (ws_size - packed_bytes - tmp_bytes - 64) / ((size_t)NUM_PIDS * 4);
        hblk = (int)(cap < HBLK_MAX ? cap : HBLK_MAX);
        if (hblk < 1) hblk = 1;
    }

    unsigned int* packed = (unsigned int*)d_ws;
    unsigned int* tbl = (unsigned int*)((char*)d_ws + packed_bytes);
    unsigned long long* tmp =
        (unsigned long long*)((char*)tbl + (size_t)hblk * NUM_PIDS * 4);
    float* acc = (float*)((char*)tmp + tmp_bytes);

    int nb = (Q2 + 255) / 256;
    if (nb > 4096) nb = 4096;

    zero_acc_kernel<<<1, 64, 0, stream>>>(acc);
    mse_kernel<<<nb, 256, 0, stream>>>(pred, track, pid, recon,
                                       (u32x2*)packed, packed, Q2, n);
    hist_kernel<<<hblk, 1024, 0, stream>>>((const uint4*)packed, tbl, n / 4,
                                           packed, n);
    dim3 g1((NUM_PIDS + 255) / 256, NCH);
    reduce1_kernel<<<g1, 256, 0, stream>>>(tbl, tmp, hblk);
    reduce2_kernel<<<(NUM_PIDS + 255) / 256, 256, 0, stream>>>(tmp, acc);
    final_kernel<<<1, 64, 0, stream>>>(acc, (float*)d_out);
}